// Round 1
// baseline (559.507 us; speedup 1.0000x reference)
//
#include <hip/hip_runtime.h>
#include <math.h>

// ---------------- constants ----------------
constexpr float DLO[8] = {-0.010597401784997278f, 0.032883011666982945f, 0.030841381835986965f,
                          -0.18703481171888114f, -0.02798376941698385f, 0.6308807679295904f,
                          0.7148465705525415f, 0.23037781330885523f};
constexpr float DHI[8] = {-0.23037781330885523f, 0.7148465705525415f, -0.6308807679295904f,
                          -0.02798376941698385f, 0.18703481171888114f, 0.030841381835986965f,
                          -0.032883011666982945f, -0.010597401784997278f};

// dwt, mode='symmetric' with pywt phase: left pad 6, right pad 7
// out[i] = sum_j xe[2i+j] * filt[7-j]
template<int N>
__device__ __forceinline__ void dwt_step(const float* in, float* a, float* d) {
  constexpr int NO = (N + 7) / 2;
#pragma unroll
  for (int i = 0; i < NO; i++) {
    float sa = 0.f, sd = 0.f;
#pragma unroll
    for (int j = 0; j < 8; j++) {
      int rel = 2 * i + j - 6;
      int idx = (rel < 0) ? (-rel - 1) : ((rel >= N) ? (2 * N - rel - 1) : rel);
      float v = in[idx];
      sa = fmaf(v, DLO[7 - j], sa);
      sd = fmaf(v, DHI[7 - j], sd);
    }
    a[i] = sa;
    d[i] = sd;
  }
}

// ---------------- kernel 1: features ----------------
// combined[b][row][s], rows: 0..20 x, 21..31 |rfft|, 32..38 cA4, 39..45 cD4,
// 46..53 cD3, 54..63 cD2, 64..77 cD1
__global__ __launch_bounds__(256) void features_kernel(const float* __restrict__ x,
                                                       float* __restrict__ comb) {
  __shared__ float xl[256 * 21];
  const int tid = threadIdx.x;
  const int g0 = blockIdx.x * 256;
  for (int idx = tid; idx < 256 * 21; idx += 256) xl[idx] = x[g0 * 21 + idx];
  __syncthreads();

  const int gid = g0 + tid;
  const int b = gid >> 10, s = gid & 1023;

  float xx[21];
#pragma unroll
  for (int t = 0; t < 21; t++) xx[t] = xl[tid * 21 + t];

  float* cb = comb + ((b * 78) << 10) + s;

  // raw copy
#pragma unroll
  for (int t = 0; t < 21; t++) cb[t << 10] = xx[t];

  // 21-point DFT magnitudes (k = 0..10)
  float ct[21], st[21];
#pragma unroll
  for (int m = 0; m < 21; m++) {
    float ang = (float)m * 0.29919930034188507f;  // 2*pi/21
    sincosf(ang, &st[m], &ct[m]);
  }
#pragma unroll
  for (int k = 0; k < 11; k++) {
    float re = 0.f, im = 0.f;
#pragma unroll
    for (int t = 0; t < 21; t++) {
      const int m = (k * t) % 21;  // compile-time under unroll
      re = fmaf(xx[t], ct[m], re);
      im = fmaf(xx[t], st[m], im);
    }
    cb[(21 + k) << 10] = sqrtf(re * re + im * im);
  }

  // db4 wavedec, 4 levels
  float a1[14], d1[14];
  dwt_step<21>(xx, a1, d1);
#pragma unroll
  for (int i = 0; i < 14; i++) cb[(64 + i) << 10] = d1[i];
  float a2[10], d2[10];
  dwt_step<14>(a1, a2, d2);
#pragma unroll
  for (int i = 0; i < 10; i++) cb[(54 + i) << 10] = d2[i];
  float a3[8], d3[8];
  dwt_step<10>(a2, a3, d3);
#pragma unroll
  for (int i = 0; i < 8; i++) cb[(46 + i) << 10] = d3[i];
  float a4[7], d4[7];
  dwt_step<8>(a3, a4, d4);
#pragma unroll
  for (int i = 0; i < 7; i++) {
    cb[(32 + i) << 10] = a4[i];
    cb[(39 + i) << 10] = d4[i];
  }
}

// ---------------- kernel 0: transpose conv weights [64][78][3] -> [78][3][64] ----------------
__global__ __launch_bounds__(256) void transpose_w_kernel(const float* __restrict__ cw,
                                                          float* __restrict__ wT) {
  int idx = blockIdx.x * 256 + threadIdx.x;
  if (idx < 64 * 78 * 3) {
    int o = idx / 234;
    int r = idx - o * 234;
    int c = r / 3;
    int k = r - c * 3;
    wT[(c * 3 + k) * 64 + o] = cw[idx];
  }
}

// ---------------- kernel 2: conv(k=3,pad=1) + bias + relu + maxpool2 ----------------
// block: one b, 32 pooled positions, all 64 channels. thread: 4 s-pos x 4 ch.
__global__ __launch_bounds__(256) void conv_pool_kernel(const float* __restrict__ comb,
                                                        const float* __restrict__ wT,
                                                        const float* __restrict__ cbias,
                                                        float* __restrict__ y) {
  __shared__ __align__(16) float xs[39 * 66];
  __shared__ __align__(16) float wl[39 * 192];
  __shared__ float bl[64];

  const int tid = threadIdx.x;
  const int b = blockIdx.y;
  const int t0 = blockIdx.x * 32;
  const int s0 = 2 * t0;
  const int tc = tid & 15;   // position group: pooled t0+2tc, t0+2tc+1
  const int tr = tid >> 4;   // channel group: o = 4*tr .. 4*tr+3

  if (tid < 64) bl[tid] = cbias[tid];

  float acc[4][4];
#pragma unroll
  for (int i = 0; i < 4; i++)
#pragma unroll
    for (int n = 0; n < 4; n++) acc[i][n] = 0.f;

  for (int cs = 0; cs < 78; cs += 39) {
    __syncthreads();
    for (int idx = tid; idx < 39 * 66; idx += 256) {
      int c = idx / 66;
      int j = idx - c * 66;
      int s = s0 - 1 + j;
      xs[idx] = (s >= 0 && s < 1024) ? comb[((b * 78 + cs + c) << 10) + s] : 0.f;
    }
    for (int idx = tid; idx < 39 * 192; idx += 256) wl[idx] = wT[cs * 192 + idx];
    __syncthreads();

    for (int c = 0; c < 39; c++) {
      float xv[6];
#pragma unroll
      for (int i = 0; i < 6; i++) xv[i] = xs[c * 66 + 4 * tc + i];
#pragma unroll
      for (int k = 0; k < 3; k++) {
        float4 w4 = ((const float4*)wl)[(c * 3 + k) * 16 + tr];
#pragma unroll
        for (int i = 0; i < 4; i++) {
          acc[i][0] = fmaf(xv[i + k], w4.x, acc[i][0]);
          acc[i][1] = fmaf(xv[i + k], w4.y, acc[i][1]);
          acc[i][2] = fmaf(xv[i + k], w4.z, acc[i][2]);
          acc[i][3] = fmaf(xv[i + k], w4.w, acc[i][3]);
        }
      }
    }
  }

  // bias + relu + pool pairs -> y[b][t][64]
  const int o0 = tr * 4;
  float4 v0, v1;
  float* pv0 = &v0.x;
  float* pv1 = &v1.x;
#pragma unroll
  for (int n = 0; n < 4; n++) {
    float bi = bl[o0 + n];
    pv0[n] = fmaxf(fmaxf(acc[0][n], acc[1][n]) + bi, 0.f);
    pv1[n] = fmaxf(fmaxf(acc[2][n], acc[3][n]) + bi, 0.f);
  }
  const int t = t0 + 2 * tc;
  ((float4*)y)[(b * 512 + t) * 16 + tr] = v0;
  ((float4*)y)[(b * 512 + t + 1) * 16 + tr] = v1;
}

// ---------------- kernel 3: X_proj = y @ w_ih^T + (b_ih + b_hh) ----------------
// rows R = b*512 + t (131072 rows of 64), out 128 gates per row.
__global__ __launch_bounds__(256) void proj_kernel(const float* __restrict__ y,
                                                   const float* __restrict__ w_ih,
                                                   const float* __restrict__ b_ih,
                                                   const float* __restrict__ b_hh,
                                                   float* __restrict__ Xp) {
  __shared__ __align__(16) float yl[32 * 68];
  __shared__ __align__(16) float wl[128 * 68];
  __shared__ float bl[128];

  const int tid = threadIdx.x;
  const int R0 = blockIdx.x * 32;

  for (int idx = tid; idx < 2048; idx += 256) {
    int r = idx >> 6, j = idx & 63;
    yl[r * 68 + j] = y[R0 * 64 + idx];
  }
  for (int idx = tid; idx < 8192; idx += 256) {
    int g = idx >> 6, j = idx & 63;
    wl[g * 68 + j] = w_ih[idx];
  }
  if (tid < 128) bl[tid] = b_ih[tid] + b_hh[tid];
  __syncthreads();

  const int rq = tid & 7, gq = tid >> 3;
  const int r0 = rq * 4, g0 = gq * 4;
  float acc[4][4];
#pragma unroll
  for (int i = 0; i < 4; i++)
#pragma unroll
    for (int n = 0; n < 4; n++) acc[i][n] = 0.f;

  for (int jq = 0; jq < 16; jq++) {
    const int j = jq * 4;
    float4 yv[4], wv[4];
#pragma unroll
    for (int i = 0; i < 4; i++) yv[i] = *(const float4*)&yl[(r0 + i) * 68 + j];
#pragma unroll
    for (int n = 0; n < 4; n++) wv[n] = *(const float4*)&wl[(g0 + n) * 68 + j];
#pragma unroll
    for (int i = 0; i < 4; i++)
#pragma unroll
      for (int n = 0; n < 4; n++) {
        acc[i][n] = fmaf(yv[i].x, wv[n].x, acc[i][n]);
        acc[i][n] = fmaf(yv[i].y, wv[n].y, acc[i][n]);
        acc[i][n] = fmaf(yv[i].z, wv[n].z, acc[i][n]);
        acc[i][n] = fmaf(yv[i].w, wv[n].w, acc[i][n]);
      }
  }

#pragma unroll
  for (int i = 0; i < 4; i++) {
    float4 o;
    o.x = acc[i][0] + bl[g0];
    o.y = acc[i][1] + bl[g0 + 1];
    o.z = acc[i][2] + bl[g0 + 2];
    o.w = acc[i][3] + bl[g0 + 3];
    *(float4*)&Xp[(R0 + r0 + i) * 128 + g0] = o;
  }
}

// ---------------- kernel 4: LSTM recurrence + fc ----------------
// one wave per batch element. lane L computes gates L and L+64.
// L<32: i_L, g_L ; L>=32: f_{L-32}, o_{L-32}. h,c live on lanes 0..31.
__device__ __forceinline__ float fsig(float x) { return 1.0f / (1.0f + __expf(-x)); }
__device__ __forceinline__ float ftanh(float x) {
  x = fmaxf(fminf(x, 15.f), -15.f);
  float e = __expf(2.f * x);
  return (e - 1.f) / (e + 1.f);
}

__global__ __launch_bounds__(64) void lstm_fc_kernel(const float* __restrict__ Xp,
                                                     const float* __restrict__ w_hh,
                                                     const float* __restrict__ fc_w,
                                                     const float* __restrict__ fc_b,
                                                     float* __restrict__ out) {
  const int b = blockIdx.x;
  const int L = threadIdx.x;

  float wA[32], wB[32];
#pragma unroll
  for (int k = 0; k < 32; k++) {
    wA[k] = w_hh[L * 32 + k];           // gate row L
    wB[k] = w_hh[(L + 64) * 32 + k];    // gate row L+64
  }

  const float* xp = Xp + b * 512 * 128;
  float h = 0.f, c = 0.f;
  float nA = xp[L], nB = xp[L + 64];

  for (int t = 0; t < 512; t++) {
    float gA = nA, gB = nB;
    if (t < 511) {
      nA = xp[(t + 1) * 128 + L];
      nB = xp[(t + 1) * 128 + 64 + L];
    }
#pragma unroll
    for (int k = 0; k < 32; k++) {
      float hk = __shfl(h, k);
      gA = fmaf(hk, wA[k], gA);
      gB = fmaf(hk, wB[k], gB);
    }
    float sA = fsig(gA);                                // i (lanes<32) / f (lanes>=32)
    float sB = (L < 32) ? ftanh(gB) : fsig(gB);         // g (lanes<32) / o (lanes>=32)
    float fv = __shfl_down(sA, 32);                     // f_j to lane j
    float ov = __shfl_down(sB, 32);                     // o_j to lane j
    c = fmaf(fv, c, sA * sB);                           // c = f*c + i*g (valid lanes<32)
    h = ov * ftanh(c);                                  // h = o*tanh(c)
  }

  float v = (L < 32) ? h * fc_w[L] : 0.f;
#pragma unroll
  for (int off = 32; off > 0; off >>= 1) v += __shfl_down(v, off);
  if (L == 0) out[b] = v + fc_b[0];
}

// ---------------- launch ----------------
extern "C" void kernel_launch(void* const* d_in, const int* in_sizes, int n_in,
                              void* d_out, int out_size, void* d_ws, size_t ws_size,
                              hipStream_t stream) {
  const float* x      = (const float*)d_in[0];  // [256,1024,21]
  const float* conv_w = (const float*)d_in[1];  // [64,78,3]
  const float* conv_b = (const float*)d_in[2];  // [64]
  const float* w_ih   = (const float*)d_in[3];  // [128,64]
  const float* w_hh   = (const float*)d_in[4];  // [128,32]
  const float* b_ih   = (const float*)d_in[5];  // [128]
  const float* b_hh   = (const float*)d_in[6];  // [128]
  const float* fc_w   = (const float*)d_in[7];  // [1,32]
  const float* fc_b   = (const float*)d_in[8];  // [1]
  float* out = (float*)d_out;                   // [256,1]

  char* wsb = (char*)d_ws;
  float* comb = (float*)wsb;                          // 256*78*1024*4 = 81,788,928 B
  float* Xp   = (float*)wsb;                          // aliases comb (dead after conv)
  float* y    = (float*)(wsb + 81788928);             // 256*512*64*4 = 33,554,432 B
  float* wT   = (float*)(wsb + 81788928 + 33554432);  // 78*3*64*4 = 59,904 B

  transpose_w_kernel<<<dim3(59), dim3(256), 0, stream>>>(conv_w, wT);
  features_kernel<<<dim3(1024), dim3(256), 0, stream>>>(x, comb);
  conv_pool_kernel<<<dim3(16, 256), dim3(256), 0, stream>>>(comb, wT, conv_b, y);
  proj_kernel<<<dim3(4096), dim3(256), 0, stream>>>(y, w_ih, b_ih, b_hh, Xp);
  lstm_fc_kernel<<<dim3(256), dim3(64), 0, stream>>>(Xp, w_hh, fc_w, fc_b, out);
}

// Round 2
// 450.663 us; speedup vs baseline: 1.2415x; 1.2415x over previous
//
#include <hip/hip_runtime.h>
#include <math.h>

// ---------------- constants ----------------
constexpr float DLO[8] = {-0.010597401784997278f, 0.032883011666982945f, 0.030841381835986965f,
                          -0.18703481171888114f, -0.02798376941698385f, 0.6308807679295904f,
                          0.7148465705525415f, 0.23037781330885523f};
constexpr float DHI[8] = {-0.23037781330885523f, 0.7148465705525415f, -0.6308807679295904f,
                          -0.02798376941698385f, 0.18703481171888114f, 0.030841381835986965f,
                          -0.032883011666982945f, -0.010597401784997278f};

// dwt, mode='symmetric' with pywt phase: left pad 6, right pad 7
// out[i] = sum_j xe[2i+j] * filt[7-j]
template<int N>
__device__ __forceinline__ void dwt_step(const float* in, float* a, float* d) {
  constexpr int NO = (N + 7) / 2;
#pragma unroll
  for (int i = 0; i < NO; i++) {
    float sa = 0.f, sd = 0.f;
#pragma unroll
    for (int j = 0; j < 8; j++) {
      int rel = 2 * i + j - 6;
      int idx = (rel < 0) ? (-rel - 1) : ((rel >= N) ? (2 * N - rel - 1) : rel);
      float v = in[idx];
      sa = fmaf(v, DLO[7 - j], sa);
      sd = fmaf(v, DHI[7 - j], sd);
    }
    a[i] = sa;
    d[i] = sd;
  }
}

// ---------------- kernel 1: features ----------------
// combined[b][row][s], rows: 0..20 x, 21..31 |rfft|, 32..38 cA4, 39..45 cD4,
// 46..53 cD3, 54..63 cD2, 64..77 cD1
__global__ __launch_bounds__(256) void features_kernel(const float* __restrict__ x,
                                                       float* __restrict__ comb) {
  __shared__ float xl[256 * 21];
  const int tid = threadIdx.x;
  const int g0 = blockIdx.x * 256;
  for (int idx = tid; idx < 256 * 21; idx += 256) xl[idx] = x[g0 * 21 + idx];
  __syncthreads();

  const int gid = g0 + tid;
  const int b = gid >> 10, s = gid & 1023;

  float xx[21];
#pragma unroll
  for (int t = 0; t < 21; t++) xx[t] = xl[tid * 21 + t];

  float* cb = comb + ((b * 78) << 10) + s;

  // raw copy
#pragma unroll
  for (int t = 0; t < 21; t++) cb[t << 10] = xx[t];

  // 21-point DFT magnitudes (k = 0..10)
  float ct[21], st[21];
#pragma unroll
  for (int m = 0; m < 21; m++) {
    float ang = (float)m * 0.29919930034188507f;  // 2*pi/21
    sincosf(ang, &st[m], &ct[m]);
  }
#pragma unroll
  for (int k = 0; k < 11; k++) {
    float re = 0.f, im = 0.f;
#pragma unroll
    for (int t = 0; t < 21; t++) {
      const int m = (k * t) % 21;  // compile-time under unroll
      re = fmaf(xx[t], ct[m], re);
      im = fmaf(xx[t], st[m], im);
    }
    cb[(21 + k) << 10] = sqrtf(re * re + im * im);
  }

  // db4 wavedec, 4 levels
  float a1[14], d1[14];
  dwt_step<21>(xx, a1, d1);
#pragma unroll
  for (int i = 0; i < 14; i++) cb[(64 + i) << 10] = d1[i];
  float a2[10], d2[10];
  dwt_step<14>(a1, a2, d2);
#pragma unroll
  for (int i = 0; i < 10; i++) cb[(54 + i) << 10] = d2[i];
  float a3[8], d3[8];
  dwt_step<10>(a2, a3, d3);
#pragma unroll
  for (int i = 0; i < 8; i++) cb[(46 + i) << 10] = d3[i];
  float a4[7], d4[7];
  dwt_step<8>(a3, a4, d4);
#pragma unroll
  for (int i = 0; i < 7; i++) {
    cb[(32 + i) << 10] = a4[i];
    cb[(39 + i) << 10] = d4[i];
  }
}

// ---------------- kernel 0: transpose conv weights [64][78][3] -> [78][3][64] ----------------
__global__ __launch_bounds__(256) void transpose_w_kernel(const float* __restrict__ cw,
                                                          float* __restrict__ wT) {
  int idx = blockIdx.x * 256 + threadIdx.x;
  if (idx < 64 * 78 * 3) {
    int o = idx / 234;
    int r = idx - o * 234;
    int c = r / 3;
    int k = r - c * 3;
    wT[(c * 3 + k) * 64 + o] = cw[idx];
  }
}

// ---------------- kernel 2: conv(k=3,pad=1) + bias + relu + maxpool2 ----------------
// block: one b, 32 pooled positions, all 64 channels. thread: 4 s-pos x 4 ch.
__global__ __launch_bounds__(256) void conv_pool_kernel(const float* __restrict__ comb,
                                                        const float* __restrict__ wT,
                                                        const float* __restrict__ cbias,
                                                        float* __restrict__ y) {
  __shared__ __align__(16) float xs[39 * 66];
  __shared__ __align__(16) float wl[39 * 192];
  __shared__ float bl[64];

  const int tid = threadIdx.x;
  const int b = blockIdx.y;
  const int t0 = blockIdx.x * 32;
  const int s0 = 2 * t0;
  const int tc = tid & 15;   // position group: pooled t0+2tc, t0+2tc+1
  const int tr = tid >> 4;   // channel group: o = 4*tr .. 4*tr+3

  if (tid < 64) bl[tid] = cbias[tid];

  float acc[4][4];
#pragma unroll
  for (int i = 0; i < 4; i++)
#pragma unroll
    for (int n = 0; n < 4; n++) acc[i][n] = 0.f;

  for (int cs = 0; cs < 78; cs += 39) {
    __syncthreads();
    for (int idx = tid; idx < 39 * 66; idx += 256) {
      int c = idx / 66;
      int j = idx - c * 66;
      int s = s0 - 1 + j;
      xs[idx] = (s >= 0 && s < 1024) ? comb[((b * 78 + cs + c) << 10) + s] : 0.f;
    }
    for (int idx = tid; idx < 39 * 192; idx += 256) wl[idx] = wT[cs * 192 + idx];
    __syncthreads();

    for (int c = 0; c < 39; c++) {
      float xv[6];
#pragma unroll
      for (int i = 0; i < 6; i++) xv[i] = xs[c * 66 + 4 * tc + i];
#pragma unroll
      for (int k = 0; k < 3; k++) {
        float4 w4 = ((const float4*)wl)[(c * 3 + k) * 16 + tr];
#pragma unroll
        for (int i = 0; i < 4; i++) {
          acc[i][0] = fmaf(xv[i + k], w4.x, acc[i][0]);
          acc[i][1] = fmaf(xv[i + k], w4.y, acc[i][1]);
          acc[i][2] = fmaf(xv[i + k], w4.z, acc[i][2]);
          acc[i][3] = fmaf(xv[i + k], w4.w, acc[i][3]);
        }
      }
    }
  }

  // bias + relu + pool pairs -> y[b][t][64]
  const int o0 = tr * 4;
  float4 v0, v1;
  float* pv0 = &v0.x;
  float* pv1 = &v1.x;
#pragma unroll
  for (int n = 0; n < 4; n++) {
    float bi = bl[o0 + n];
    pv0[n] = fmaxf(fmaxf(acc[0][n], acc[1][n]) + bi, 0.f);
    pv1[n] = fmaxf(fmaxf(acc[2][n], acc[3][n]) + bi, 0.f);
  }
  const int t = t0 + 2 * tc;
  ((float4*)y)[(b * 512 + t) * 16 + tr] = v0;
  ((float4*)y)[(b * 512 + t + 1) * 16 + tr] = v1;
}

// ---------------- kernel 3: X_proj = y @ w_ih^T + (b_ih + b_hh) ----------------
// rows R = b*512 + t (131072 rows of 64), out 128 gates per row.
__global__ __launch_bounds__(256) void proj_kernel(const float* __restrict__ y,
                                                   const float* __restrict__ w_ih,
                                                   const float* __restrict__ b_ih,
                                                   const float* __restrict__ b_hh,
                                                   float* __restrict__ Xp) {
  __shared__ __align__(16) float yl[32 * 68];
  __shared__ __align__(16) float wl[128 * 68];
  __shared__ float bl[128];

  const int tid = threadIdx.x;
  const int R0 = blockIdx.x * 32;

  for (int idx = tid; idx < 2048; idx += 256) {
    int r = idx >> 6, j = idx & 63;
    yl[r * 68 + j] = y[R0 * 64 + idx];
  }
  for (int idx = tid; idx < 8192; idx += 256) {
    int g = idx >> 6, j = idx & 63;
    wl[g * 68 + j] = w_ih[idx];
  }
  if (tid < 128) bl[tid] = b_ih[tid] + b_hh[tid];
  __syncthreads();

  const int rq = tid & 7, gq = tid >> 3;
  const int r0 = rq * 4, g0 = gq * 4;
  float acc[4][4];
#pragma unroll
  for (int i = 0; i < 4; i++)
#pragma unroll
    for (int n = 0; n < 4; n++) acc[i][n] = 0.f;

  for (int jq = 0; jq < 16; jq++) {
    const int j = jq * 4;
    float4 yv[4], wv[4];
#pragma unroll
    for (int i = 0; i < 4; i++) yv[i] = *(const float4*)&yl[(r0 + i) * 68 + j];
#pragma unroll
    for (int n = 0; n < 4; n++) wv[n] = *(const float4*)&wl[(g0 + n) * 68 + j];
#pragma unroll
    for (int i = 0; i < 4; i++)
#pragma unroll
      for (int n = 0; n < 4; n++) {
        acc[i][n] = fmaf(yv[i].x, wv[n].x, acc[i][n]);
        acc[i][n] = fmaf(yv[i].y, wv[n].y, acc[i][n]);
        acc[i][n] = fmaf(yv[i].z, wv[n].z, acc[i][n]);
        acc[i][n] = fmaf(yv[i].w, wv[n].w, acc[i][n]);
      }
  }

#pragma unroll
  for (int i = 0; i < 4; i++) {
    float4 o;
    o.x = acc[i][0] + bl[g0];
    o.y = acc[i][1] + bl[g0 + 1];
    o.z = acc[i][2] + bl[g0 + 2];
    o.w = acc[i][3] + bl[g0 + 3];
    *(float4*)&Xp[(R0 + r0 + i) * 128 + g0] = o;
  }
}

// ---------------- kernel 4: LSTM recurrence + fc ----------------
// one wave per batch element. lane L computes gates L and L+64.
// L<32: i_L, g_L ; L>=32: f_{L-32}, o_{L-32}. h,c live on lanes 0..31.
//
// R1 change: h-broadcast via v_readlane (SGPR, no DS/lgkmcnt waits) instead of
// 32x ds_bpermute; 4-way split accumulators; v_rcp instead of fp32 divide;
// t-loop unrolled 4 with 4-step register prefetch of Xp (1 wave/CU has no
// TLP to hide the ~900cyc HBM miss).
__device__ __forceinline__ float fsig(float x) {
  float e = __expf(-x);
  return __builtin_amdgcn_rcpf(1.0f + e);
}
__device__ __forceinline__ float ftanh(float x) {
  x = fmaxf(fminf(x, 15.f), -15.f);
  float e = __expf(2.f * x);
  return (e - 1.f) * __builtin_amdgcn_rcpf(e + 1.f);
}
__device__ __forceinline__ float bcast_lane(float v, int k) {
  return __uint_as_float(__builtin_amdgcn_readlane(__float_as_uint(v), k));
}

__global__ __launch_bounds__(64) void lstm_fc_kernel(const float* __restrict__ Xp,
                                                     const float* __restrict__ w_hh,
                                                     const float* __restrict__ fc_w,
                                                     const float* __restrict__ fc_b,
                                                     float* __restrict__ out) {
  const int b = blockIdx.x;
  const int L = threadIdx.x;

  float wA[32], wB[32];
#pragma unroll
  for (int k = 0; k < 32; k++) {
    wA[k] = w_hh[L * 32 + k];           // gate row L
    wB[k] = w_hh[(L + 64) * 32 + k];    // gate row L+64
  }

  const float* xp = Xp + b * 512 * 128;
  float h = 0.f, c = 0.f;

  // 4-deep prefetch registers
  float pA[4], pB[4];
#pragma unroll
  for (int u = 0; u < 4; u++) {
    pA[u] = xp[u * 128 + L];
    pB[u] = xp[u * 128 + 64 + L];
  }

  for (int t0 = 0; t0 < 512; t0 += 4) {
    float cAr[4], cBr[4];
#pragma unroll
    for (int u = 0; u < 4; u++) { cAr[u] = pA[u]; cBr[u] = pB[u]; }
    if (t0 + 4 < 512) {
#pragma unroll
      for (int u = 0; u < 4; u++) {
        pA[u] = xp[(t0 + 4 + u) * 128 + L];
        pB[u] = xp[(t0 + 4 + u) * 128 + 64 + L];
      }
    }
#pragma unroll
    for (int u = 0; u < 4; u++) {
      float aA[4], aB[4];
      aA[0] = cAr[u]; aA[1] = 0.f; aA[2] = 0.f; aA[3] = 0.f;
      aB[0] = cBr[u]; aB[1] = 0.f; aB[2] = 0.f; aB[3] = 0.f;
#pragma unroll
      for (int k = 0; k < 32; k++) {
        float hk = bcast_lane(h, k);    // v_readlane_b32: uniform, no DS wait
        aA[k & 3] = fmaf(hk, wA[k], aA[k & 3]);
        aB[k & 3] = fmaf(hk, wB[k], aB[k & 3]);
      }
      float gA = (aA[0] + aA[1]) + (aA[2] + aA[3]);
      float gB = (aB[0] + aB[1]) + (aB[2] + aB[3]);
      float sA = fsig(gA);                           // i (lanes<32) / f (lanes>=32)
      float sB = (L < 32) ? ftanh(gB) : fsig(gB);    // g (lanes<32) / o (lanes>=32)
      float fv = __shfl_down(sA, 32);                // f_j to lane j
      float ov = __shfl_down(sB, 32);                // o_j to lane j
      c = fmaf(fv, c, sA * sB);                      // c = f*c + i*g (valid lanes<32)
      h = ov * ftanh(c);                             // h = o*tanh(c)
    }
  }

  float v = (L < 32) ? h * fc_w[L] : 0.f;
#pragma unroll
  for (int off = 32; off > 0; off >>= 1) v += __shfl_down(v, off);
  if (L == 0) out[b] = v + fc_b[0];
}

// ---------------- launch ----------------
extern "C" void kernel_launch(void* const* d_in, const int* in_sizes, int n_in,
                              void* d_out, int out_size, void* d_ws, size_t ws_size,
                              hipStream_t stream) {
  const float* x      = (const float*)d_in[0];  // [256,1024,21]
  const float* conv_w = (const float*)d_in[1];  // [64,78,3]
  const float* conv_b = (const float*)d_in[2];  // [64]
  const float* w_ih   = (const float*)d_in[3];  // [128,64]
  const float* w_hh   = (const float*)d_in[4];  // [128,32]
  const float* b_ih   = (const float*)d_in[5];  // [128]
  const float* b_hh   = (const float*)d_in[6];  // [128]
  const float* fc_w   = (const float*)d_in[7];  // [1,32]
  const float* fc_b   = (const float*)d_in[8];  // [1]
  float* out = (float*)d_out;                   // [256,1]

  char* wsb = (char*)d_ws;
  float* comb = (float*)wsb;                          // 256*78*1024*4 = 81,788,928 B
  float* Xp   = (float*)wsb;                          // aliases comb (dead after conv)
  float* y    = (float*)(wsb + 81788928);             // 256*512*64*4 = 33,554,432 B
  float* wT   = (float*)(wsb + 81788928 + 33554432);  // 78*3*64*4 = 59,904 B

  transpose_w_kernel<<<dim3(59), dim3(256), 0, stream>>>(conv_w, wT);
  features_kernel<<<dim3(1024), dim3(256), 0, stream>>>(x, comb);
  conv_pool_kernel<<<dim3(16, 256), dim3(256), 0, stream>>>(comb, wT, conv_b, y);
  proj_kernel<<<dim3(4096), dim3(256), 0, stream>>>(y, w_ih, b_ih, b_hh, Xp);
  lstm_fc_kernel<<<dim3(256), dim3(64), 0, stream>>>(Xp, w_hh, fc_w, fc_b, out);
}

// Round 3
// 424.989 us; speedup vs baseline: 1.3165x; 1.0604x over previous
//
#include <hip/hip_runtime.h>
#include <math.h>

// ---------------- constants ----------------
constexpr float DLO[8] = {-0.010597401784997278f, 0.032883011666982945f, 0.030841381835986965f,
                          -0.18703481171888114f, -0.02798376941698385f, 0.6308807679295904f,
                          0.7148465705525415f, 0.23037781330885523f};
constexpr float DHI[8] = {-0.23037781330885523f, 0.7148465705525415f, -0.6308807679295904f,
                          -0.02798376941698385f, 0.18703481171888114f, 0.030841381835986965f,
                          -0.032883011666982945f, -0.010597401784997278f};

// dwt, mode='symmetric' with pywt phase: left pad 6, right pad 7
// out[i] = sum_j xe[2i+j] * filt[7-j]
template<int N>
__device__ __forceinline__ void dwt_step(const float* in, float* a, float* d) {
  constexpr int NO = (N + 7) / 2;
#pragma unroll
  for (int i = 0; i < NO; i++) {
    float sa = 0.f, sd = 0.f;
#pragma unroll
    for (int j = 0; j < 8; j++) {
      int rel = 2 * i + j - 6;
      int idx = (rel < 0) ? (-rel - 1) : ((rel >= N) ? (2 * N - rel - 1) : rel);
      float v = in[idx];
      sa = fmaf(v, DLO[7 - j], sa);
      sd = fmaf(v, DHI[7 - j], sd);
    }
    a[i] = sa;
    d[i] = sd;
  }
}

// ---------------- kernel 1: features ----------------
// combined[b][row][s], rows: 0..20 x, 21..31 |rfft|, 32..38 cA4, 39..45 cD4,
// 46..53 cD3, 54..63 cD2, 64..77 cD1
__global__ __launch_bounds__(256) void features_kernel(const float* __restrict__ x,
                                                       float* __restrict__ comb) {
  __shared__ float xl[256 * 21];
  const int tid = threadIdx.x;
  const int g0 = blockIdx.x * 256;
  for (int idx = tid; idx < 256 * 21; idx += 256) xl[idx] = x[g0 * 21 + idx];
  __syncthreads();

  const int gid = g0 + tid;
  const int b = gid >> 10, s = gid & 1023;

  float xx[21];
#pragma unroll
  for (int t = 0; t < 21; t++) xx[t] = xl[tid * 21 + t];

  float* cb = comb + ((b * 78) << 10) + s;

  // raw copy
#pragma unroll
  for (int t = 0; t < 21; t++) cb[t << 10] = xx[t];

  // 21-point DFT magnitudes (k = 0..10)
  float ct[21], st[21];
#pragma unroll
  for (int m = 0; m < 21; m++) {
    float ang = (float)m * 0.29919930034188507f;  // 2*pi/21
    sincosf(ang, &st[m], &ct[m]);
  }
#pragma unroll
  for (int k = 0; k < 11; k++) {
    float re = 0.f, im = 0.f;
#pragma unroll
    for (int t = 0; t < 21; t++) {
      const int m = (k * t) % 21;  // compile-time under unroll
      re = fmaf(xx[t], ct[m], re);
      im = fmaf(xx[t], st[m], im);
    }
    cb[(21 + k) << 10] = sqrtf(re * re + im * im);
  }

  // db4 wavedec, 4 levels
  float a1[14], d1[14];
  dwt_step<21>(xx, a1, d1);
#pragma unroll
  for (int i = 0; i < 14; i++) cb[(64 + i) << 10] = d1[i];
  float a2[10], d2[10];
  dwt_step<14>(a1, a2, d2);
#pragma unroll
  for (int i = 0; i < 10; i++) cb[(54 + i) << 10] = d2[i];
  float a3[8], d3[8];
  dwt_step<10>(a2, a3, d3);
#pragma unroll
  for (int i = 0; i < 8; i++) cb[(46 + i) << 10] = d3[i];
  float a4[7], d4[7];
  dwt_step<8>(a3, a4, d4);
#pragma unroll
  for (int i = 0; i < 7; i++) {
    cb[(32 + i) << 10] = a4[i];
    cb[(39 + i) << 10] = d4[i];
  }
}

// ---------------- kernel 0: transpose conv weights [64][78][3] -> [78][3][64] ----------------
__global__ __launch_bounds__(256) void transpose_w_kernel(const float* __restrict__ cw,
                                                          float* __restrict__ wT) {
  int idx = blockIdx.x * 256 + threadIdx.x;
  if (idx < 64 * 78 * 3) {
    int o = idx / 234;
    int r = idx - o * 234;
    int c = r / 3;
    int k = r - c * 3;
    wT[(c * 3 + k) * 64 + o] = cw[idx];
  }
}

// ---------------- kernel 2: conv(k=3,pad=1) + bias + relu + maxpool2 ----------------
// block: one b, 32 pooled positions, all 64 channels. thread: 4 s-pos x 4 ch.
// R2: xs stride padded 66->68 so the 6-float window is one b128 + one b64 LDS read.
__global__ __launch_bounds__(256) void conv_pool_kernel(const float* __restrict__ comb,
                                                        const float* __restrict__ wT,
                                                        const float* __restrict__ cbias,
                                                        float* __restrict__ y) {
  __shared__ __align__(16) float xs[39 * 68];
  __shared__ __align__(16) float wl[39 * 192];
  __shared__ float bl[64];

  const int tid = threadIdx.x;
  const int b = blockIdx.y;
  const int t0 = blockIdx.x * 32;
  const int s0 = 2 * t0;
  const int tc = tid & 15;   // position group: pooled t0+2tc, t0+2tc+1
  const int tr = tid >> 4;   // channel group: o = 4*tr .. 4*tr+3

  if (tid < 64) bl[tid] = cbias[tid];

  float acc[4][4];
#pragma unroll
  for (int i = 0; i < 4; i++)
#pragma unroll
    for (int n = 0; n < 4; n++) acc[i][n] = 0.f;

  for (int cs = 0; cs < 78; cs += 39) {
    __syncthreads();
    for (int idx = tid; idx < 39 * 66; idx += 256) {
      int c = idx / 66;
      int j = idx - c * 66;
      int s = s0 - 1 + j;
      xs[c * 68 + j] = (s >= 0 && s < 1024) ? comb[((b * 78 + cs + c) << 10) + s] : 0.f;
    }
    for (int idx = tid; idx < 39 * 192; idx += 256) wl[idx] = wT[cs * 192 + idx];
    __syncthreads();

    for (int c = 0; c < 39; c++) {
      const float* xrow = &xs[c * 68 + 4 * tc];   // 16B-aligned (68*4=272 ≡ 0 mod 16)
      float4 x4 = *(const float4*)xrow;
      float2 x2 = *(const float2*)(xrow + 4);
      float xv[6] = {x4.x, x4.y, x4.z, x4.w, x2.x, x2.y};
#pragma unroll
      for (int k = 0; k < 3; k++) {
        float4 w4 = ((const float4*)wl)[(c * 3 + k) * 16 + tr];
#pragma unroll
        for (int i = 0; i < 4; i++) {
          acc[i][0] = fmaf(xv[i + k], w4.x, acc[i][0]);
          acc[i][1] = fmaf(xv[i + k], w4.y, acc[i][1]);
          acc[i][2] = fmaf(xv[i + k], w4.z, acc[i][2]);
          acc[i][3] = fmaf(xv[i + k], w4.w, acc[i][3]);
        }
      }
    }
  }

  // bias + relu + pool pairs -> y[b][t][64]
  const int o0 = tr * 4;
  float4 v0, v1;
  float* pv0 = &v0.x;
  float* pv1 = &v1.x;
#pragma unroll
  for (int n = 0; n < 4; n++) {
    float bi = bl[o0 + n];
    pv0[n] = fmaxf(fmaxf(acc[0][n], acc[1][n]) + bi, 0.f);
    pv1[n] = fmaxf(fmaxf(acc[2][n], acc[3][n]) + bi, 0.f);
  }
  const int t = t0 + 2 * tc;
  ((float4*)y)[(b * 512 + t) * 16 + tr] = v0;
  ((float4*)y)[(b * 512 + t + 1) * 16 + tr] = v1;
}

// ---------------- kernel 3: X_proj = y @ w_ih^T + (b_ih + b_hh) ----------------
// rows R = b*512 + t (131072 rows of 64), out 128 gates per row.
__global__ __launch_bounds__(256) void proj_kernel(const float* __restrict__ y,
                                                   const float* __restrict__ w_ih,
                                                   const float* __restrict__ b_ih,
                                                   const float* __restrict__ b_hh,
                                                   float* __restrict__ Xp) {
  __shared__ __align__(16) float yl[32 * 68];
  __shared__ __align__(16) float wl[128 * 68];
  __shared__ float bl[128];

  const int tid = threadIdx.x;
  const int R0 = blockIdx.x * 32;

  for (int idx = tid; idx < 2048; idx += 256) {
    int r = idx >> 6, j = idx & 63;
    yl[r * 68 + j] = y[R0 * 64 + idx];
  }
  for (int idx = tid; idx < 8192; idx += 256) {
    int g = idx >> 6, j = idx & 63;
    wl[g * 68 + j] = w_ih[idx];
  }
  if (tid < 128) bl[tid] = b_ih[tid] + b_hh[tid];
  __syncthreads();

  const int rq = tid & 7, gq = tid >> 3;
  const int r0 = rq * 4, g0 = gq * 4;
  float acc[4][4];
#pragma unroll
  for (int i = 0; i < 4; i++)
#pragma unroll
    for (int n = 0; n < 4; n++) acc[i][n] = 0.f;

  for (int jq = 0; jq < 16; jq++) {
    const int j = jq * 4;
    float4 yv[4], wv[4];
#pragma unroll
    for (int i = 0; i < 4; i++) yv[i] = *(const float4*)&yl[(r0 + i) * 68 + j];
#pragma unroll
    for (int n = 0; n < 4; n++) wv[n] = *(const float4*)&wl[(g0 + n) * 68 + j];
#pragma unroll
    for (int i = 0; i < 4; i++)
#pragma unroll
      for (int n = 0; n < 4; n++) {
        acc[i][n] = fmaf(yv[i].x, wv[n].x, acc[i][n]);
        acc[i][n] = fmaf(yv[i].y, wv[n].y, acc[i][n]);
        acc[i][n] = fmaf(yv[i].z, wv[n].z, acc[i][n]);
        acc[i][n] = fmaf(yv[i].w, wv[n].w, acc[i][n]);
      }
  }

#pragma unroll
  for (int i = 0; i < 4; i++) {
    float4 o;
    o.x = acc[i][0] + bl[g0];
    o.y = acc[i][1] + bl[g0 + 1];
    o.z = acc[i][2] + bl[g0 + 2];
    o.w = acc[i][3] + bl[g0 + 3];
    *(float4*)&Xp[(R0 + r0 + i) * 128 + g0] = o;
  }
}

// ---------------- kernel 4: LSTM recurrence + fc ----------------
// one wave per batch element. lane L computes gates L and L+64.
// L<32: i_L, g_L ; L>=32: f_{L-32}, o_{L-32}. h,c live on lanes 0..31.
//
// R2 changes (per-step critical path):
//  - v_permlane32_swap_b32 (VALU) replaces both ds_bpermute half-swaps
//  - float2 gate accumulators via __builtin_elementwise_fma -> v_pk_fma_f32
//  - merged sB transcendental: ONE exp + ONE rcp covers tanh(g) (lanes<32)
//    and sigmoid(o) (lanes>=32) via operand select
typedef float float2v __attribute__((ext_vector_type(2)));

__device__ __forceinline__ float bcast_lane(float v, int k) {
  return __uint_as_float(__builtin_amdgcn_readlane(__float_as_uint(v), k));
}

#if __has_builtin(__builtin_amdgcn_permlane32_swap)
// returns, for lanes 0..31, the value held by lane (j+32); VALU-only, no DS.
__device__ __forceinline__ float swap_half(float x) {
  auto r = __builtin_amdgcn_permlane32_swap(__float_as_uint(x), __float_as_uint(x),
                                            false, false);
  return __uint_as_float(r[1]);
}
#else
__device__ __forceinline__ float swap_half(float x) { return __shfl_down(x, 32); }
#endif

__global__ __launch_bounds__(64) void lstm_fc_kernel(const float* __restrict__ Xp,
                                                     const float* __restrict__ w_hh,
                                                     const float* __restrict__ fc_w,
                                                     const float* __restrict__ fc_b,
                                                     float* __restrict__ out) {
  const int b = blockIdx.x;
  const int L = threadIdx.x;
  const bool lo = (L < 32);

  float2v w2[32];
#pragma unroll
  for (int k = 0; k < 32; k++) {
    w2[k].x = w_hh[L * 32 + k];           // gate row L      (i for lo, f for hi)
    w2[k].y = w_hh[(L + 64) * 32 + k];    // gate row L+64   (g for lo, o for hi)
  }

  const float* xp = Xp + b * 512 * 128;
  float h = 0.f, c = 0.f;

  // 4-deep prefetch registers
  float pA[4], pB[4];
#pragma unroll
  for (int u = 0; u < 4; u++) {
    pA[u] = xp[u * 128 + L];
    pB[u] = xp[u * 128 + 64 + L];
  }

  for (int t0 = 0; t0 < 512; t0 += 4) {
    float cAr[4], cBr[4];
#pragma unroll
    for (int u = 0; u < 4; u++) { cAr[u] = pA[u]; cBr[u] = pB[u]; }
    if (t0 + 4 < 512) {
#pragma unroll
      for (int u = 0; u < 4; u++) {
        pA[u] = xp[(t0 + 4 + u) * 128 + L];
        pB[u] = xp[(t0 + 4 + u) * 128 + 64 + L];
      }
    }
#pragma unroll
    for (int u = 0; u < 4; u++) {
      float2v a2[4];
      a2[0] = (float2v){cAr[u], cBr[u]};
      a2[1] = (float2v){0.f, 0.f};
      a2[2] = (float2v){0.f, 0.f};
      a2[3] = (float2v){0.f, 0.f};
#pragma unroll
      for (int k = 0; k < 32; k++) {
        float hk = bcast_lane(h, k);            // v_readlane_b32 (SGPR broadcast)
        float2v hk2 = (float2v){hk, hk};
        a2[k & 3] = __builtin_elementwise_fma(hk2, w2[k], a2[k & 3]);  // v_pk_fma_f32
      }
      float2v s01 = a2[0] + a2[1];
      float2v s23 = a2[2] + a2[3];
      float2v g2 = s01 + s23;
      float gA = g2.x, gB = g2.y;

      // sA = sigmoid(gA) on all lanes (i for lo, f for hi)
      float eA = __expf(-gA);
      float sA = __builtin_amdgcn_rcpf(1.0f + eA);

      // sB: tanh(gB) on lo lanes (g), sigmoid(gB) on hi lanes (o) — one exp+rcp
      float gBc = fmaxf(fminf(gB, 15.f), -15.f);
      float arg = lo ? (2.f * gBc) : (-gB);
      float eB = __expf(arg);
      float num = lo ? (eB - 1.f) : 1.f;
      float sB = num * __builtin_amdgcn_rcpf(eB + 1.f);

      float fv = swap_half(sA);                 // sig(f_j) -> lane j
      float ov = swap_half(sB);                 // sig(o_j) -> lane j
      c = fmaf(fv, c, sA * sB);                 // c = f*c + i*g   (valid lanes<32)
      float cc = fmaxf(fminf(c, 15.f), -15.f);
      float ec = __expf(2.f * cc);
      h = ov * (ec - 1.f) * __builtin_amdgcn_rcpf(ec + 1.f);  // h = o*tanh(c)
    }
  }

  float v = lo ? h * fc_w[L] : 0.f;
#pragma unroll
  for (int off = 32; off > 0; off >>= 1) v += __shfl_down(v, off);
  if (L == 0) out[b] = v + fc_b[0];
}

// ---------------- launch ----------------
extern "C" void kernel_launch(void* const* d_in, const int* in_sizes, int n_in,
                              void* d_out, int out_size, void* d_ws, size_t ws_size,
                              hipStream_t stream) {
  const float* x      = (const float*)d_in[0];  // [256,1024,21]
  const float* conv_w = (const float*)d_in[1];  // [64,78,3]
  const float* conv_b = (const float*)d_in[2];  // [64]
  const float* w_ih   = (const float*)d_in[3];  // [128,64]
  const float* w_hh   = (const float*)d_in[4];  // [128,32]
  const float* b_ih   = (const float*)d_in[5];  // [128]
  const float* b_hh   = (const float*)d_in[6];  // [128]
  const float* fc_w   = (const float*)d_in[7];  // [1,32]
  const float* fc_b   = (const float*)d_in[8];  // [1]
  float* out = (float*)d_out;                   // [256,1]

  char* wsb = (char*)d_ws;
  float* comb = (float*)wsb;                          // 256*78*1024*4 = 81,788,928 B
  float* Xp   = (float*)wsb;                          // aliases comb (dead after conv)
  float* y    = (float*)(wsb + 81788928);             // 256*512*64*4 = 33,554,432 B
  float* wT   = (float*)(wsb + 81788928 + 33554432);  // 78*3*64*4 = 59,904 B

  transpose_w_kernel<<<dim3(59), dim3(256), 0, stream>>>(conv_w, wT);
  features_kernel<<<dim3(1024), dim3(256), 0, stream>>>(x, comb);
  conv_pool_kernel<<<dim3(16, 256), dim3(256), 0, stream>>>(comb, wT, conv_b, y);
  proj_kernel<<<dim3(4096), dim3(256), 0, stream>>>(y, w_ih, b_ih, b_hh, Xp);
  lstm_fc_kernel<<<dim3(256), dim3(64), 0, stream>>>(Xp, w_hh, fc_w, fc_b, out);
}